// Round 2
// baseline (464.498 us; speedup 1.0000x reference)
//
#include <hip/hip_runtime.h>
#include <hip/hip_bf16.h>

typedef __bf16 bf16;
typedef __bf16 bf16x8 __attribute__((ext_vector_type(8)));
typedef float f32x4 __attribute__((ext_vector_type(4)));

__device__ inline bf16x8 cvt8(const float* __restrict__ p) {
  float4 a = *(const float4*)p;
  float4 b = *(const float4*)(p + 4);
  bf16x8 r;
  r[0] = (bf16)a.x; r[1] = (bf16)a.y; r[2] = (bf16)a.z; r[3] = (bf16)a.w;
  r[4] = (bf16)b.x; r[5] = (bf16)b.y; r[6] = (bf16)b.z; r[7] = (bf16)b.w;
  return r;
}

// ---------------------------------------------------------------- transpose + fp32->bf16 cast
__global__ __launch_bounds__(256) void transpose_cast_k(const float* __restrict__ in,
                                                        bf16* __restrict__ out,
                                                        int R, int C) {
  __shared__ bf16 T[32][33];
  int tc = blockIdx.x * 32, tr = blockIdx.y * 32;
  int c = threadIdx.x & 31, r8 = threadIdx.x >> 5;
#pragma unroll
  for (int i = 0; i < 4; i++) {
    int r = r8 + i * 8;
    T[r][c] = (bf16)in[(long)(tr + r) * C + tc + c];
  }
  __syncthreads();
#pragma unroll
  for (int i = 0; i < 4; i++) {
    int r = r8 + i * 8;
    out[(long)(tc + r) * R + tr + c] = T[c][r];
  }
}

// ---------------------------------------------------------------- GEMM (A MxK, Bt NxK bf16)
// EPI==0: A = fp32 x; epilogue scatters into q(b,h,n,d), k(b,h,n,d), vT(b,h,d,n)
// EPI==1: A = bf16 attention-out stored in (b,h,tok,d) layout (qb buffer); plain fp32 C write
template <int EPI>
__global__ __launch_bounds__(256) void gemm_bt(const float* __restrict__ Af,
                                               const bf16* __restrict__ Aq,
                                               const bf16* __restrict__ Bt,
                                               const float* __restrict__ bias,
                                               int M, int N, int K,
                                               float* __restrict__ out,
                                               bf16* __restrict__ qb,
                                               bf16* __restrict__ kb,
                                               bf16* __restrict__ vT) {
  __shared__ __align__(16) bf16 As[128][40];  // 32 k + 8 pad (80B stride, 16B-aligned)
  __shared__ __align__(16) bf16 Bs[128][40];

  const int tid = threadIdx.x;
  const int lane = tid & 63;
  const int w = tid >> 6;
  const int wm = (w & 1) * 64;
  const int wn = (w >> 1) * 64;
  const int quad = lane >> 4;
  const int l16 = lane & 15;

  const int m0 = blockIdx.y * 128;
  const int n0 = blockIdx.x * 128;

  const int ar = tid >> 2;       // 0..63
  const int ac = (tid & 3) * 8;  // 0,8,16,24

  f32x4 acc[4][4];
#pragma unroll
  for (int i = 0; i < 4; i++)
#pragma unroll
    for (int j = 0; j < 4; j++) acc[i][j] = f32x4{0.f, 0.f, 0.f, 0.f};

  for (int k0 = 0; k0 < K; k0 += 32) {
    __syncthreads();
    bf16x8 va0, va1;
    if (EPI == 0) {
      va0 = cvt8(Af + (long)(m0 + ar) * K + k0 + ac);
      va1 = cvt8(Af + (long)(m0 + ar + 64) * K + k0 + ac);
    } else {
      // A row m = b*1024+tok, col k = h*64+dc, stored at ((b*16+h)*1024+tok)*64+dc
      int k = k0 + ac;
      int hh = k >> 6, dc = k & 63;
      int m1 = m0 + ar, m2 = m0 + ar + 64;
      va0 = *(const bf16x8*)(Aq + (((long)((m1 >> 10) * 16 + hh) * 1024 + (m1 & 1023)) * 64) + dc);
      va1 = *(const bf16x8*)(Aq + (((long)((m2 >> 10) * 16 + hh) * 1024 + (m2 & 1023)) * 64) + dc);
    }
    bf16x8 vb0 = *(const bf16x8*)(Bt + (long)(n0 + ar) * K + k0 + ac);
    bf16x8 vb1 = *(const bf16x8*)(Bt + (long)(n0 + ar + 64) * K + k0 + ac);
    *(bf16x8*)&As[ar][ac] = va0;
    *(bf16x8*)&As[ar + 64][ac] = va1;
    *(bf16x8*)&Bs[ar][ac] = vb0;
    *(bf16x8*)&Bs[ar + 64][ac] = vb1;
    __syncthreads();

    bf16x8 af[4], bfr[4];
#pragma unroll
    for (int i = 0; i < 4; i++) {
      af[i] = *(const bf16x8*)&As[wm + i * 16 + l16][quad * 8];
      bfr[i] = *(const bf16x8*)&Bs[wn + i * 16 + l16][quad * 8];
    }
#pragma unroll
    for (int i = 0; i < 4; i++)
#pragma unroll
      for (int j = 0; j < 4; j++)
        acc[i][j] = __builtin_amdgcn_mfma_f32_16x16x32_bf16(af[i], bfr[j], acc[i][j], 0, 0, 0);
  }

  // epilogue: C[row=quad*4+r][col=l16] per 16x16 frag (verified m89/m91 layout)
#pragma unroll
  for (int i = 0; i < 4; i++) {
#pragma unroll
    for (int j = 0; j < 4; j++) {
#pragma unroll
      for (int r = 0; r < 4; r++) {
        int mg = m0 + wm + i * 16 + quad * 4 + r;
        int ng = n0 + wn + j * 16 + l16;
        float v = acc[i][j][r] + bias[ng];
        if (EPI == 1) {
          out[(long)mg * N + ng] = v;
        } else {
          bf16 hv = (bf16)v;
          int bi = mg >> 10, ntok = mg & 1023;
          int which = ng >> 10, rem = ng & 1023;
          int head = rem >> 6, dc = rem & 63;
          int bh = bi * 16 + head;
          if (which == 0)
            qb[((long)bh * 1024 + ntok) * 64 + dc] = hv;
          else if (which == 1)
            kb[((long)bh * 1024 + ntok) * 64 + dc] = hv;
          else
            vT[((long)bh * 64 + dc) * 1024 + ntok] = hv;
        }
      }
    }
  }
}

// ---------------------------------------------------------------- QK norm + RoPE + l2 (in place)
// one wave per (b,h,ntok); lane = channel j in [0,64)
__global__ __launch_bounds__(256) void prep_k(bf16* __restrict__ qb, bf16* __restrict__ kb,
                                              const float* __restrict__ qg,
                                              const float* __restrict__ kg) {
  int gw = blockIdx.x * 4 + (threadIdx.x >> 6);
  int lane = threadIdx.x & 63;
  int ntok = gw & 1023;
  int bh = gw >> 10;
  long base = ((long)bh * 1024 + ntok) * 64 + lane;

  float qv = (float)qb[base];
  float kv = (float)kb[base];

  // RMSNorm over d=64
  float sq = qv * qv, sk = kv * kv;
#pragma unroll
  for (int m = 32; m; m >>= 1) {
    sq += __shfl_xor(sq, m, 64);
    sk += __shfl_xor(sk, m, 64);
  }
  qv *= rsqrtf(sq * (1.0f / 64.0f) + 1e-6f) * qg[lane];
  kv *= rsqrtf(sk * (1.0f / 64.0f) + 1e-6f) * kg[lane];

  // 2D axial RoPE: side=32, n_freq=16
  int half = lane & 31;
  int fi = half & 15;
  float freq = exp2f((float)fi * (-13.287712379549449f / 16.0f));  // 10000^(-fi/16)
  int prow = ntok >> 5, pcol = ntok & 31;
  float ang = (half < 16 ? (float)prow : (float)pcol) * freq;
  float s, c;
  __sincosf(ang, &s, &c);
  float qp = __shfl_xor(qv, 32, 64);
  float kp = __shfl_xor(kv, 32, 64);
  float sgn = (lane < 32) ? -1.0f : 1.0f;
  qv = qv * c + sgn * qp * s;
  kv = kv * c + sgn * kp * s;

  // l2 normalize; fold COS_SIM_SCALE=8 into q
  float nq = qv * qv, nk = kv * kv;
#pragma unroll
  for (int m = 32; m; m >>= 1) {
    nq += __shfl_xor(nq, m, 64);
    nk += __shfl_xor(nk, m, 64);
  }
  qv *= rsqrtf(nq) * 8.0f;
  kv *= rsqrtf(nk);

  qb[base] = (bf16)qv;
  kb[base] = (bf16)kv;
}

// ---------------------------------------------------------------- flash attention
// block = (bh, 64-query tile); wave = 16 queries; K-tile = 32 keys
// O is written back INTO qb (each wave reads only the Q rows it later overwrites)
__global__ __launch_bounds__(256) void attn_k(bf16* __restrict__ qb,
                                              const bf16* __restrict__ kb,
                                              const bf16* __restrict__ vT) {
  __shared__ __align__(16) bf16 Ks[32][72];     // keys x d   (144B stride)
  __shared__ __align__(16) bf16 Vs[64][40];     // d x keys   (80B stride)
  __shared__ __align__(16) bf16 Ps[4][16][40];  // per-wave P

  const int tid = threadIdx.x;
  const int lane = tid & 63;
  const int w = tid >> 6;
  const int quad = lane >> 4;
  const int l16 = lane & 15;

  const int bh = blockIdx.y;
  const int q0 = blockIdx.x * 64 + w * 16;

  // Q fragments (q already holds cos-sim scale 8)
  const long qrow = ((long)bh * 1024 + q0 + l16) * 64;
  bf16x8 aq0 = *(const bf16x8*)(qb + qrow + quad * 8);
  bf16x8 aq1 = *(const bf16x8*)(qb + qrow + 32 + quad * 8);

  f32x4 acc_o[4];
#pragma unroll
  for (int i = 0; i < 4; i++) acc_o[i] = f32x4{0.f, 0.f, 0.f, 0.f};
  float m_r[4], l_r[4];
#pragma unroll
  for (int r = 0; r < 4; r++) {
    m_r[r] = -1e30f;
    l_r[r] = 0.0f;
  }

  const int kr = tid >> 3, kc = (tid & 7) * 8;  // K staging: 32 rows x 64 d
  const int vr = tid >> 2, vc = (tid & 3) * 8;  // V staging: 64 rows x 32 keys
  const bf16* kbase = kb + (long)bh * 1024 * 64;
  const bf16* vbase = vT + (long)bh * 64 * 1024;

  for (int kt = 0; kt < 1024; kt += 32) {
    __syncthreads();
    *(bf16x8*)&Ks[kr][kc] = *(const bf16x8*)(kbase + (long)(kt + kr) * 64 + kc);
    *(bf16x8*)&Vs[vr][vc] = *(const bf16x8*)(vbase + (long)vr * 1024 + kt + vc);
    __syncthreads();

    // S = Q K^T  (16q x 32keys)
    f32x4 s0 = f32x4{0.f, 0.f, 0.f, 0.f}, s1 = f32x4{0.f, 0.f, 0.f, 0.f};
    {
      bf16x8 b00 = *(const bf16x8*)&Ks[l16][quad * 8];
      bf16x8 b01 = *(const bf16x8*)&Ks[l16][32 + quad * 8];
      s0 = __builtin_amdgcn_mfma_f32_16x16x32_bf16(aq0, b00, s0, 0, 0, 0);
      s0 = __builtin_amdgcn_mfma_f32_16x16x32_bf16(aq1, b01, s0, 0, 0, 0);
      bf16x8 b10 = *(const bf16x8*)&Ks[16 + l16][quad * 8];
      bf16x8 b11 = *(const bf16x8*)&Ks[16 + l16][32 + quad * 8];
      s1 = __builtin_amdgcn_mfma_f32_16x16x32_bf16(aq0, b10, s1, 0, 0, 0);
      s1 = __builtin_amdgcn_mfma_f32_16x16x32_bf16(aq1, b11, s1, 0, 0, 0);
    }

    // online softmax per query row (row = quad*4+r; 16 key-cols across l16, x2 groups)
    float alpha[4], p0[4], p1[4];
#pragma unroll
    for (int r = 0; r < 4; r++) {
      float mt = fmaxf(s0[r], s1[r]);
#pragma unroll
      for (int m = 8; m; m >>= 1) mt = fmaxf(mt, __shfl_xor(mt, m, 64));
      float mnew = fmaxf(m_r[r], mt);
      alpha[r] = __expf(m_r[r] - mnew);
      m_r[r] = mnew;
      p0[r] = __expf(s0[r] - mnew);
      p1[r] = __expf(s1[r] - mnew);
      float rs = p0[r] + p1[r];
#pragma unroll
      for (int m = 8; m; m >>= 1) rs += __shfl_xor(rs, m, 64);
      l_r[r] = l_r[r] * alpha[r] + rs;
    }

    // P (C-layout) -> LDS -> A-layout fragment
#pragma unroll
    for (int r = 0; r < 4; r++) {
      Ps[w][quad * 4 + r][l16] = (bf16)p0[r];
      Ps[w][quad * 4 + r][16 + l16] = (bf16)p1[r];
    }
    __syncthreads();
    bf16x8 ap = *(const bf16x8*)&Ps[w][l16][quad * 8];

    // O = O*alpha + P @ V
#pragma unroll
    for (int i = 0; i < 4; i++)
#pragma unroll
      for (int r = 0; r < 4; r++) acc_o[i][r] *= alpha[r];
#pragma unroll
    for (int i = 0; i < 4; i++) {
      bf16x8 bv = *(const bf16x8*)&Vs[i * 16 + l16][quad * 8];
      acc_o[i] = __builtin_amdgcn_mfma_f32_16x16x32_bf16(ap, bv, acc_o[i], 0, 0, 0);
    }
  }

  // write O back into qb in (b,h,tok,d) layout — rows this wave owns
#pragma unroll
  for (int i = 0; i < 4; i++) {
#pragma unroll
    for (int r = 0; r < 4; r++) {
      long base = ((long)bh * 1024 + q0 + quad * 4 + r) * 64 + i * 16 + l16;
      qb[base] = (bf16)(acc_o[i][r] / l_r[r]);
    }
  }
}

// ---------------------------------------------------------------- launcher
extern "C" void kernel_launch(void* const* d_in, const int* in_sizes, int n_in,
                              void* d_out, int out_size, void* d_ws, size_t ws_size,
                              hipStream_t stream) {
  (void)in_sizes; (void)n_in; (void)out_size; (void)ws_size;
  const float* x     = (const float*)d_in[0];
  const float* w_qkv = (const float*)d_in[1];
  const float* b_qkv = (const float*)d_in[2];
  const float* q_g   = (const float*)d_in[3];
  const float* k_g   = (const float*)d_in[4];
  const float* w_out = (const float*)d_in[5];
  const float* b_out = (const float*)d_in[6];
  float* out = (float*)d_out;

  char* ws = (char*)d_ws;
  bf16* wqkvT = (bf16*)ws; ws += (long)3072 * 1024 * 2;      // 6 MB
  bf16* woT   = (bf16*)ws; ws += (long)1024 * 1024 * 2;      // 2 MB
  bf16* qb    = (bf16*)ws; ws += (long)128 * 1024 * 64 * 2;  // 16 MB (q, then attention O)
  bf16* kb    = (bf16*)ws; ws += (long)128 * 1024 * 64 * 2;  // 16 MB
  bf16* vT    = (bf16*)ws; ws += (long)128 * 64 * 1024 * 2;  // 16 MB   (total 56 MB)

  transpose_cast_k<<<dim3(3072 / 32, 1024 / 32), 256, 0, stream>>>(w_qkv, wqkvT, 1024, 3072);
  transpose_cast_k<<<dim3(1024 / 32, 1024 / 32), 256, 0, stream>>>(w_out, woT, 1024, 1024);
  gemm_bt<0><<<dim3(3072 / 128, 8192 / 128), 256, 0, stream>>>(x, (const bf16*)nullptr, wqkvT,
                                                               b_qkv, 8192, 3072, 1024,
                                                               (float*)nullptr, qb, kb, vT);
  prep_k<<<dim3(131072 / 4), 256, 0, stream>>>(qb, kb, q_g, k_g);
  attn_k<<<dim3(16, 128), 256, 0, stream>>>(qb, kb, vT);
  gemm_bt<1><<<dim3(1024 / 128, 8192 / 128), 256, 0, stream>>>((const float*)nullptr, qb, woT,
                                                               b_out, 8192, 1024, 1024,
                                                               out, (bf16*)nullptr,
                                                               (bf16*)nullptr, (bf16*)nullptr);
}

// Round 3
// 373.553 us; speedup vs baseline: 1.2435x; 1.2435x over previous
//
#include <hip/hip_runtime.h>
#include <hip/hip_bf16.h>

typedef __bf16 bf16;
typedef __bf16 bf16x8 __attribute__((ext_vector_type(8)));
typedef __bf16 bf16x4 __attribute__((ext_vector_type(4)));
typedef float f32x4 __attribute__((ext_vector_type(4)));

__device__ inline bf16x8 cvt8(const float* __restrict__ p) {
  float4 a = *(const float4*)p;
  float4 b = *(const float4*)(p + 4);
  bf16x8 r;
  r[0] = (bf16)a.x; r[1] = (bf16)a.y; r[2] = (bf16)a.z; r[3] = (bf16)a.w;
  r[4] = (bf16)b.x; r[5] = (bf16)b.y; r[6] = (bf16)b.z; r[7] = (bf16)b.w;
  return r;
}

// ---------------------------------------------------------------- transpose + fp32->bf16 cast
__global__ __launch_bounds__(256) void transpose_cast_k(const float* __restrict__ in,
                                                        bf16* __restrict__ out,
                                                        int R, int C) {
  __shared__ bf16 T[32][33];
  int tc = blockIdx.x * 32, tr = blockIdx.y * 32;
  int c = threadIdx.x & 31, r8 = threadIdx.x >> 5;
#pragma unroll
  for (int i = 0; i < 4; i++) {
    int r = r8 + i * 8;
    T[r][c] = (bf16)in[(long)(tr + r) * C + tc + c];
  }
  __syncthreads();
#pragma unroll
  for (int i = 0; i < 4; i++) {
    int r = r8 + i * 8;
    out[(long)(tc + r) * R + tr + c] = T[c][r];
  }
}

// ---------------------------------------------------------------- GEMM (A MxK, Bt NxK bf16)
// EPI==0: A = fp32 x; epilogue scatters into q(b,h,n,d), k(b,h,n,d), vT(b,h,d,n)
// EPI==1: A = bf16 attention-out stored in (b,h,tok,d) layout (qb buffer); plain fp32 C write
template <int EPI>
__global__ __launch_bounds__(256) void gemm_bt(const float* __restrict__ Af,
                                               const bf16* __restrict__ Aq,
                                               const bf16* __restrict__ Bt,
                                               const float* __restrict__ bias,
                                               int M, int N, int K,
                                               float* __restrict__ out,
                                               bf16* __restrict__ qb,
                                               bf16* __restrict__ kb,
                                               bf16* __restrict__ vT) {
  __shared__ __align__(16) bf16 As[128][40];  // 32 k + 8 pad (80B stride, 16B-aligned)
  __shared__ __align__(16) bf16 Bs[128][40];

  const int tid = threadIdx.x;
  const int lane = tid & 63;
  const int w = tid >> 6;
  const int wm = (w & 1) * 64;
  const int wn = (w >> 1) * 64;
  const int quad = lane >> 4;
  const int l16 = lane & 15;

  const int m0 = blockIdx.y * 128;
  const int n0 = blockIdx.x * 128;

  const int ar = tid >> 2;       // 0..63
  const int ac = (tid & 3) * 8;  // 0,8,16,24

  f32x4 acc[4][4];
#pragma unroll
  for (int i = 0; i < 4; i++)
#pragma unroll
    for (int j = 0; j < 4; j++) acc[i][j] = f32x4{0.f, 0.f, 0.f, 0.f};

  for (int k0 = 0; k0 < K; k0 += 32) {
    __syncthreads();
    bf16x8 va0, va1;
    if (EPI == 0) {
      va0 = cvt8(Af + (long)(m0 + ar) * K + k0 + ac);
      va1 = cvt8(Af + (long)(m0 + ar + 64) * K + k0 + ac);
    } else {
      // A row m = b*1024+tok, col k = h*64+dc, stored at ((b*16+h)*1024+tok)*64+dc
      int k = k0 + ac;
      int hh = k >> 6, dc = k & 63;
      int m1 = m0 + ar, m2 = m0 + ar + 64;
      va0 = *(const bf16x8*)(Aq + (((long)((m1 >> 10) * 16 + hh) * 1024 + (m1 & 1023)) * 64) + dc);
      va1 = *(const bf16x8*)(Aq + (((long)((m2 >> 10) * 16 + hh) * 1024 + (m2 & 1023)) * 64) + dc);
    }
    bf16x8 vb0 = *(const bf16x8*)(Bt + (long)(n0 + ar) * K + k0 + ac);
    bf16x8 vb1 = *(const bf16x8*)(Bt + (long)(n0 + ar + 64) * K + k0 + ac);
    *(bf16x8*)&As[ar][ac] = va0;
    *(bf16x8*)&As[ar + 64][ac] = va1;
    *(bf16x8*)&Bs[ar][ac] = vb0;
    *(bf16x8*)&Bs[ar + 64][ac] = vb1;
    __syncthreads();

    bf16x8 af[4], bfr[4];
#pragma unroll
    for (int i = 0; i < 4; i++) {
      af[i] = *(const bf16x8*)&As[wm + i * 16 + l16][quad * 8];
      bfr[i] = *(const bf16x8*)&Bs[wn + i * 16 + l16][quad * 8];
    }
#pragma unroll
    for (int i = 0; i < 4; i++)
#pragma unroll
      for (int j = 0; j < 4; j++)
        acc[i][j] = __builtin_amdgcn_mfma_f32_16x16x32_bf16(af[i], bfr[j], acc[i][j], 0, 0, 0);
  }

  // epilogue: C[row=quad*4+r][col=l16] per 16x16 frag (verified m89/m91 layout)
#pragma unroll
  for (int i = 0; i < 4; i++) {
#pragma unroll
    for (int j = 0; j < 4; j++) {
#pragma unroll
      for (int r = 0; r < 4; r++) {
        int mg = m0 + wm + i * 16 + quad * 4 + r;
        int ng = n0 + wn + j * 16 + l16;
        float v = acc[i][j][r] + bias[ng];
        if (EPI == 1) {
          out[(long)mg * N + ng] = v;
        } else {
          bf16 hv = (bf16)v;
          int bi = mg >> 10, ntok = mg & 1023;
          int which = ng >> 10, rem = ng & 1023;
          int head = rem >> 6, dc = rem & 63;
          int bh = bi * 16 + head;
          if (which == 0)
            qb[((long)bh * 1024 + ntok) * 64 + dc] = hv;
          else if (which == 1)
            kb[((long)bh * 1024 + ntok) * 64 + dc] = hv;
          else
            vT[((long)bh * 64 + dc) * 1024 + ntok] = hv;
        }
      }
    }
  }
}

// ---------------------------------------------------------------- QK norm + RoPE + l2 (in place)
// one wave per (b,h,ntok); lane = channel j in [0,64)
__global__ __launch_bounds__(256) void prep_k(bf16* __restrict__ qb, bf16* __restrict__ kb,
                                              const float* __restrict__ qg,
                                              const float* __restrict__ kg) {
  int gw = blockIdx.x * 4 + (threadIdx.x >> 6);
  int lane = threadIdx.x & 63;
  int ntok = gw & 1023;
  int bh = gw >> 10;
  long base = ((long)bh * 1024 + ntok) * 64 + lane;

  float qv = (float)qb[base];
  float kv = (float)kb[base];

  // RMSNorm over d=64
  float sq = qv * qv, sk = kv * kv;
#pragma unroll
  for (int m = 32; m; m >>= 1) {
    sq += __shfl_xor(sq, m, 64);
    sk += __shfl_xor(sk, m, 64);
  }
  qv *= rsqrtf(sq * (1.0f / 64.0f) + 1e-6f) * qg[lane];
  kv *= rsqrtf(sk * (1.0f / 64.0f) + 1e-6f) * kg[lane];

  // 2D axial RoPE: side=32, n_freq=16
  int half = lane & 31;
  int fi = half & 15;
  float freq = exp2f((float)fi * (-13.287712379549449f / 16.0f));  // 10000^(-fi/16)
  int prow = ntok >> 5, pcol = ntok & 31;
  float ang = (half < 16 ? (float)prow : (float)pcol) * freq;
  float s, c;
  __sincosf(ang, &s, &c);
  float qp = __shfl_xor(qv, 32, 64);
  float kp = __shfl_xor(kv, 32, 64);
  float sgn = (lane < 32) ? -1.0f : 1.0f;
  qv = qv * c + sgn * qp * s;
  kv = kv * c + sgn * kp * s;

  // l2 normalize; fold COS_SIM_SCALE=8 into q
  float nq = qv * qv, nk = kv * kv;
#pragma unroll
  for (int m = 32; m; m >>= 1) {
    nq += __shfl_xor(nq, m, 64);
    nk += __shfl_xor(nk, m, 64);
  }
  qv *= rsqrtf(nq) * 8.0f;
  kv *= rsqrtf(nk);

  qb[base] = (bf16)qv;
  kb[base] = (bf16)kv;
}

// ---------------------------------------------------------------- flash attention (fixed-max softmax)
// Scores bounded: s = 8*cos in [-8,8] -> p = exp(s-8), no online max/rescale needed.
// Computes S^T = K·Q^T so each lane's C-column is ONE query: l-sum is per-lane (+2 shfl at end),
// P->LDS is 4x ds_write_b64, PV is O^T = V^T·P with V^T already staged, O write is packed b64.
// block = (bh, 64-query tile); wave = 16 queries; K-tile = 64 keys. O overwrites qb rows in-place.
__global__ __launch_bounds__(256) void attn_k(bf16* __restrict__ qb,
                                              const bf16* __restrict__ kb,
                                              const bf16* __restrict__ vT) {
  __shared__ __align__(16) bf16 Ks[64][72];     // keys x d
  __shared__ __align__(16) bf16 Vs[64][72];     // d x keys
  __shared__ __align__(16) bf16 Ps[4][16][72];  // per-wave P[q][key]

  const int tid = threadIdx.x;
  const int lane = tid & 63;
  const int w = tid >> 6;
  const int quad = lane >> 4;
  const int l16 = lane & 15;

  const int bh = blockIdx.y;
  const int q0 = blockIdx.x * 64 + w * 16;

  // Q fragments (q already holds cos-sim scale 8); used as mfma B-operand for S^T = K·Q^T
  const long qrow = ((long)bh * 1024 + q0 + l16) * 64;
  bf16x8 aq0 = *(const bf16x8*)(qb + qrow + quad * 8);
  bf16x8 aq1 = *(const bf16x8*)(qb + qrow + 32 + quad * 8);

  f32x4 o[4];
#pragma unroll
  for (int i = 0; i < 4; i++) o[i] = f32x4{0.f, 0.f, 0.f, 0.f};
  float lsum = 0.0f;

  const int sr = tid >> 3, sc = (tid & 7) * 8;  // staging: 32 rows x 64 cols per pass
  const bf16* kbase = kb + (long)bh * 65536;
  const bf16* vbase = vT + (long)bh * 65536;

  for (int kt = 0; kt < 1024; kt += 64) {
    __syncthreads();
    *(bf16x8*)&Ks[sr][sc]      = *(const bf16x8*)(kbase + (long)(kt + sr) * 64 + sc);
    *(bf16x8*)&Ks[sr + 32][sc] = *(const bf16x8*)(kbase + (long)(kt + sr + 32) * 64 + sc);
    *(bf16x8*)&Vs[sr][sc]      = *(const bf16x8*)(vbase + (long)sr * 1024 + kt + sc);
    *(bf16x8*)&Vs[sr + 32][sc] = *(const bf16x8*)(vbase + (long)(sr + 32) * 1024 + kt + sc);
    __syncthreads();

    // St = K_tile · Q^T (64 keys x 16 q); frag i: key = i*16+quad*4+r, q = l16
#pragma unroll
    for (int i = 0; i < 4; i++) {
      f32x4 st = f32x4{0.f, 0.f, 0.f, 0.f};
      bf16x8 kf0 = *(const bf16x8*)&Ks[i * 16 + l16][quad * 8];
      bf16x8 kf1 = *(const bf16x8*)&Ks[i * 16 + l16][32 + quad * 8];
      st = __builtin_amdgcn_mfma_f32_16x16x32_bf16(kf0, aq0, st, 0, 0, 0);
      st = __builtin_amdgcn_mfma_f32_16x16x32_bf16(kf1, aq1, st, 0, 0, 0);
      // p = exp(s - 8); accumulate per-lane l partial (all elements belong to q=l16)
      bf16x4 pk;
#pragma unroll
      for (int r = 0; r < 4; r++) {
        float p = __expf(st[r] - 8.0f);
        lsum += p;
        pk[r] = (bf16)p;
      }
      *(bf16x4*)&Ps[w][l16][i * 16 + quad * 4] = pk;
    }
    // intra-wave LDS write->read ordering (cross-lane within wave, lockstep): drain lgkm
    asm volatile("s_waitcnt lgkmcnt(0)" ::: "memory");

    bf16x8 bp0 = *(const bf16x8*)&Ps[w][l16][quad * 8];
    bf16x8 bp1 = *(const bf16x8*)&Ps[w][l16][32 + quad * 8];

    // O^T += V^T_tile · P ; frag i: d = i*16+quad*4+r, q = l16
#pragma unroll
    for (int i = 0; i < 4; i++) {
      bf16x8 vf0 = *(const bf16x8*)&Vs[i * 16 + l16][quad * 8];
      bf16x8 vf1 = *(const bf16x8*)&Vs[i * 16 + l16][32 + quad * 8];
      o[i] = __builtin_amdgcn_mfma_f32_16x16x32_bf16(vf0, bp0, o[i], 0, 0, 0);
      o[i] = __builtin_amdgcn_mfma_f32_16x16x32_bf16(vf1, bp1, o[i], 0, 0, 0);
    }
  }

  // l for q=l16: reduce partials over the 4 quads
  lsum += __shfl_xor(lsum, 16, 64);
  lsum += __shfl_xor(lsum, 32, 64);
  float inv = 1.0f / lsum;

  // write O back into qb rows this wave owns (packed 4x bf16 = 8B stores)
#pragma unroll
  for (int i = 0; i < 4; i++) {
    bf16x4 ov;
#pragma unroll
    for (int r = 0; r < 4; r++) ov[r] = (bf16)(o[i][r] * inv);
    *(bf16x4*)(qb + qrow + i * 16 + quad * 4) = ov;
  }
}

// ---------------------------------------------------------------- launcher
extern "C" void kernel_launch(void* const* d_in, const int* in_sizes, int n_in,
                              void* d_out, int out_size, void* d_ws, size_t ws_size,
                              hipStream_t stream) {
  (void)in_sizes; (void)n_in; (void)out_size; (void)ws_size;
  const float* x     = (const float*)d_in[0];
  const float* w_qkv = (const float*)d_in[1];
  const float* b_qkv = (const float*)d_in[2];
  const float* q_g   = (const float*)d_in[3];
  const float* k_g   = (const float*)d_in[4];
  const float* w_out = (const float*)d_in[5];
  const float* b_out = (const float*)d_in[6];
  float* out = (float*)d_out;

  char* ws = (char*)d_ws;
  bf16* wqkvT = (bf16*)ws; ws += (long)3072 * 1024 * 2;      // 6 MB
  bf16* woT   = (bf16*)ws; ws += (long)1024 * 1024 * 2;      // 2 MB
  bf16* qb    = (bf16*)ws; ws += (long)128 * 1024 * 64 * 2;  // 16 MB (q, then attention O)
  bf16* kb    = (bf16*)ws; ws += (long)128 * 1024 * 64 * 2;  // 16 MB
  bf16* vT    = (bf16*)ws; ws += (long)128 * 64 * 1024 * 2;  // 16 MB   (total 56 MB)

  transpose_cast_k<<<dim3(3072 / 32, 1024 / 32), 256, 0, stream>>>(w_qkv, wqkvT, 1024, 3072);
  transpose_cast_k<<<dim3(1024 / 32, 1024 / 32), 256, 0, stream>>>(w_out, woT, 1024, 1024);
  gemm_bt<0><<<dim3(3072 / 128, 8192 / 128), 256, 0, stream>>>(x, (const bf16*)nullptr, wqkvT,
                                                               b_qkv, 8192, 3072, 1024,
                                                               (float*)nullptr, qb, kb, vT);
  prep_k<<<dim3(131072 / 4), 256, 0, stream>>>(qb, kb, q_g, k_g);
  attn_k<<<dim3(16, 128), 256, 0, stream>>>(qb, kb, vT);
  gemm_bt<1><<<dim3(1024 / 128, 8192 / 128), 256, 0, stream>>>((const float*)nullptr, qb, woT,
                                                               b_out, 8192, 1024, 1024,
                                                               out, (bf16*)nullptr,
                                                               (bf16*)nullptr, (bf16*)nullptr);
}

// Round 4
// 348.342 us; speedup vs baseline: 1.3335x; 1.0724x over previous
//
#include <hip/hip_runtime.h>
#include <hip/hip_bf16.h>
#include <cstdint>

typedef __bf16 bf16;
typedef __bf16 bf16x8 __attribute__((ext_vector_type(8)));
typedef __bf16 bf16x4 __attribute__((ext_vector_type(4)));
typedef float f32x4 __attribute__((ext_vector_type(4)));

__device__ inline bf16x8 cvt8(const float* __restrict__ p) {
  float4 a = *(const float4*)p;
  float4 b = *(const float4*)(p + 4);
  bf16x8 r;
  r[0] = (bf16)a.x; r[1] = (bf16)a.y; r[2] = (bf16)a.z; r[3] = (bf16)a.w;
  r[4] = (bf16)b.x; r[5] = (bf16)b.y; r[6] = (bf16)b.z; r[7] = (bf16)b.w;
  return r;
}

// async global->LDS, 16B per lane; LDS dest = wave-uniform base + lane*16 (m97/m104)
__device__ inline void gl_lds16(const bf16* g, bf16* l) {
  auto gp = reinterpret_cast<const __attribute__((address_space(1))) uint32_t*>(
      reinterpret_cast<uintptr_t>(g));
  auto lp = reinterpret_cast<__attribute__((address_space(3))) uint32_t*>(
      reinterpret_cast<uintptr_t>(l));
  __builtin_amdgcn_global_load_lds(gp, lp, 16, 0, 0);
}

// ---------------------------------------------------------------- fp32 -> bf16 cast
__global__ __launch_bounds__(256) void cast_k(const float* __restrict__ in,
                                              bf16* __restrict__ out) {
  long i = ((long)blockIdx.x * 256 + threadIdx.x) * 8;
  *(bf16x8*)(out + i) = cvt8(in + i);
}

// ---------------------------------------------------------------- transpose + fp32->bf16 cast
__global__ __launch_bounds__(256) void transpose_cast_k(const float* __restrict__ in,
                                                        bf16* __restrict__ out,
                                                        int R, int C) {
  __shared__ bf16 T[32][33];
  int tc = blockIdx.x * 32, tr = blockIdx.y * 32;
  int c = threadIdx.x & 31, r8 = threadIdx.x >> 5;
#pragma unroll
  for (int i = 0; i < 4; i++) {
    int r = r8 + i * 8;
    T[r][c] = (bf16)in[(long)(tr + r) * C + tc + c];
  }
  __syncthreads();
#pragma unroll
  for (int i = 0; i < 4; i++) {
    int r = r8 + i * 8;
    out[(long)(tc + r) * R + tr + c] = T[c][r];
  }
}

// ---------------------------------------------------------------- GEMM (A MxK bf16, Bt NxK bf16)
// m97 structure: unpadded 128x32 LDS tiles staged via global_load_lds_dwordx4.
// EPI==0: A = xb; epilogue scatters into q(b,h,n,d), k(b,h,n,d), vT(b,h,d,n)
// EPI==1: A = attention-out in (b,h,tok,d) layout (qb buffer), remapped loads; fp32 C write
template <int EPI>
__global__ __launch_bounds__(256) void gemm_bt(const bf16* __restrict__ A,
                                               const bf16* __restrict__ Bt,
                                               const float* __restrict__ bias,
                                               int M, int N, int K,
                                               float* __restrict__ out,
                                               bf16* __restrict__ qb,
                                               bf16* __restrict__ kb,
                                               bf16* __restrict__ vT) {
  __shared__ __align__(16) bf16 As[128][32];  // 64B row stride, unpadded (DMA layout)
  __shared__ __align__(16) bf16 Bs[128][32];

  const int tid = threadIdx.x;
  const int lane = tid & 63;
  const int w = tid >> 6;
  const int wm = (w & 1) * 64;
  const int wn = (w >> 1) * 64;
  const int quad = lane >> 4;
  const int l16 = lane & 15;

  const int m0 = blockIdx.y * 128;
  const int n0 = blockIdx.x * 128;

  // staging map: wave w covers rows [w*32, w*32+32) in two 1024B DMA calls;
  // lane -> row = base + (lane>>2), col = (lane&3)*8  => LDS offset = lane*16
  const int sr = w * 32 + (lane >> 2);
  const int sc = (lane & 3) * 8;

  f32x4 acc[4][4];
#pragma unroll
  for (int i = 0; i < 4; i++)
#pragma unroll
    for (int j = 0; j < 4; j++) acc[i][j] = f32x4{0.f, 0.f, 0.f, 0.f};

  for (int k0 = 0; k0 < K; k0 += 32) {
    __syncthreads();
    const bf16 *ga0, *ga1;
    if (EPI == 0) {
      ga0 = A + (long)(m0 + sr) * K + k0 + sc;
      ga1 = ga0 + (long)16 * K;
    } else {
      // A row m = b*1024+tok, col k = h*64+dc, stored at ((b*16+h)*1024+tok)*64+dc
      int k = k0 + sc, hh = k >> 6, dc = k & 63;
      int m1 = m0 + sr, m2 = m1 + 16;
      ga0 = A + ((long)((m1 >> 10) * 16 + hh) * 1024 + (m1 & 1023)) * 64 + dc;
      ga1 = A + ((long)((m2 >> 10) * 16 + hh) * 1024 + (m2 & 1023)) * 64 + dc;
    }
    gl_lds16(ga0, &As[w * 32][0]);
    gl_lds16(ga1, &As[w * 32 + 16][0]);
    gl_lds16(Bt + (long)(n0 + sr) * K + k0 + sc, &Bs[w * 32][0]);
    gl_lds16(Bt + (long)(n0 + sr + 16) * K + k0 + sc, &Bs[w * 32 + 16][0]);
    __syncthreads();  // compiler emits s_waitcnt vmcnt(0) before s_barrier

    bf16x8 af[4], bfr[4];
#pragma unroll
    for (int i = 0; i < 4; i++) {
      af[i] = *(const bf16x8*)&As[wm + i * 16 + l16][quad * 8];
      bfr[i] = *(const bf16x8*)&Bs[wn + i * 16 + l16][quad * 8];
    }
#pragma unroll
    for (int i = 0; i < 4; i++)
#pragma unroll
      for (int j = 0; j < 4; j++)
        acc[i][j] = __builtin_amdgcn_mfma_f32_16x16x32_bf16(af[i], bfr[j], acc[i][j], 0, 0, 0);
  }

  // epilogue: C[row=quad*4+r][col=l16] per 16x16 frag (verified m89/m91 layout)
#pragma unroll
  for (int i = 0; i < 4; i++) {
#pragma unroll
    for (int j = 0; j < 4; j++) {
#pragma unroll
      for (int r = 0; r < 4; r++) {
        int mg = m0 + wm + i * 16 + quad * 4 + r;
        int ng = n0 + wn + j * 16 + l16;
        float v = acc[i][j][r] + bias[ng];
        if (EPI == 1) {
          out[(long)mg * N + ng] = v;
        } else {
          bf16 hv = (bf16)v;
          int bi = mg >> 10, ntok = mg & 1023;
          int which = ng >> 10, rem = ng & 1023;
          int head = rem >> 6, dc = rem & 63;
          int bh = bi * 16 + head;
          if (which == 0)
            qb[((long)bh * 1024 + ntok) * 64 + dc] = hv;
          else if (which == 1)
            kb[((long)bh * 1024 + ntok) * 64 + dc] = hv;
          else
            vT[((long)bh * 64 + dc) * 1024 + ntok] = hv;
        }
      }
    }
  }
}

// ---------------------------------------------------------------- QK norm + RoPE + l2 (in place)
// one wave per (b,h,ntok); lane = channel j in [0,64)
__global__ __launch_bounds__(256) void prep_k(bf16* __restrict__ qb, bf16* __restrict__ kb,
                                              const float* __restrict__ qg,
                                              const float* __restrict__ kg) {
  int gw = blockIdx.x * 4 + (threadIdx.x >> 6);
  int lane = threadIdx.x & 63;
  int ntok = gw & 1023;
  int bh = gw >> 10;
  long base = ((long)bh * 1024 + ntok) * 64 + lane;

  float qv = (float)qb[base];
  float kv = (float)kb[base];

  // RMSNorm over d=64
  float sq = qv * qv, sk = kv * kv;
#pragma unroll
  for (int m = 32; m; m >>= 1) {
    sq += __shfl_xor(sq, m, 64);
    sk += __shfl_xor(sk, m, 64);
  }
  qv *= rsqrtf(sq * (1.0f / 64.0f) + 1e-6f) * qg[lane];
  kv *= rsqrtf(sk * (1.0f / 64.0f) + 1e-6f) * kg[lane];

  // 2D axial RoPE: side=32, n_freq=16
  int half = lane & 31;
  int fi = half & 15;
  float freq = exp2f((float)fi * (-13.287712379549449f / 16.0f));  // 10000^(-fi/16)
  int prow = ntok >> 5, pcol = ntok & 31;
  float ang = (half < 16 ? (float)prow : (float)pcol) * freq;
  float s, c;
  __sincosf(ang, &s, &c);
  float qp = __shfl_xor(qv, 32, 64);
  float kp = __shfl_xor(kv, 32, 64);
  float sgn = (lane < 32) ? -1.0f : 1.0f;
  qv = qv * c + sgn * qp * s;
  kv = kv * c + sgn * kp * s;

  // l2 normalize; fold COS_SIM_SCALE=8 into q
  float nq = qv * qv, nk = kv * kv;
#pragma unroll
  for (int m = 32; m; m >>= 1) {
    nq += __shfl_xor(nq, m, 64);
    nk += __shfl_xor(nk, m, 64);
  }
  qv *= rsqrtf(nq) * 8.0f;
  kv *= rsqrtf(nk);

  qb[base] = (bf16)qv;
  kb[base] = (bf16)kv;
}

// ---------------------------------------------------------------- flash attention (fixed-max softmax)
// s = 8*cos in [-8,8] -> p = exp(s-8); S^T = K·Q^T so lane's C-column is one query.
// block = (bh, 64-query tile); wave = 16 queries; K-tile = 64 keys. O overwrites qb in-place.
__global__ __launch_bounds__(256) void attn_k(bf16* __restrict__ qb,
                                              const bf16* __restrict__ kb,
                                              const bf16* __restrict__ vT) {
  __shared__ __align__(16) bf16 Ks[64][72];     // keys x d
  __shared__ __align__(16) bf16 Vs[64][72];     // d x keys
  __shared__ __align__(16) bf16 Ps[4][16][72];  // per-wave P[q][key]

  const int tid = threadIdx.x;
  const int lane = tid & 63;
  const int w = tid >> 6;
  const int quad = lane >> 4;
  const int l16 = lane & 15;

  const int bh = blockIdx.y;
  const int q0 = blockIdx.x * 64 + w * 16;

  const long qrow = ((long)bh * 1024 + q0 + l16) * 64;
  bf16x8 aq0 = *(const bf16x8*)(qb + qrow + quad * 8);
  bf16x8 aq1 = *(const bf16x8*)(qb + qrow + 32 + quad * 8);

  f32x4 o[4];
#pragma unroll
  for (int i = 0; i < 4; i++) o[i] = f32x4{0.f, 0.f, 0.f, 0.f};
  float lsum = 0.0f;

  const int sr = tid >> 3, sc = (tid & 7) * 8;  // staging: 32 rows x 64 cols per pass
  const bf16* kbase = kb + (long)bh * 65536;
  const bf16* vbase = vT + (long)bh * 65536;

  for (int kt = 0; kt < 1024; kt += 64) {
    __syncthreads();
    *(bf16x8*)&Ks[sr][sc]      = *(const bf16x8*)(kbase + (long)(kt + sr) * 64 + sc);
    *(bf16x8*)&Ks[sr + 32][sc] = *(const bf16x8*)(kbase + (long)(kt + sr + 32) * 64 + sc);
    *(bf16x8*)&Vs[sr][sc]      = *(const bf16x8*)(vbase + (long)sr * 1024 + kt + sc);
    *(bf16x8*)&Vs[sr + 32][sc] = *(const bf16x8*)(vbase + (long)(sr + 32) * 1024 + kt + sc);
    __syncthreads();

    // St = K_tile · Q^T (64 keys x 16 q); frag i: key = i*16+quad*4+r, q = l16
#pragma unroll
    for (int i = 0; i < 4; i++) {
      f32x4 st = f32x4{0.f, 0.f, 0.f, 0.f};
      bf16x8 kf0 = *(const bf16x8*)&Ks[i * 16 + l16][quad * 8];
      bf16x8 kf1 = *(const bf16x8*)&Ks[i * 16 + l16][32 + quad * 8];
      st = __builtin_amdgcn_mfma_f32_16x16x32_bf16(kf0, aq0, st, 0, 0, 0);
      st = __builtin_amdgcn_mfma_f32_16x16x32_bf16(kf1, aq1, st, 0, 0, 0);
      bf16x4 pk;
#pragma unroll
      for (int r = 0; r < 4; r++) {
        float p = __expf(st[r] - 8.0f);
        lsum += p;
        pk[r] = (bf16)p;
      }
      *(bf16x4*)&Ps[w][l16][i * 16 + quad * 4] = pk;
    }
    asm volatile("s_waitcnt lgkmcnt(0)" ::: "memory");

    bf16x8 bp0 = *(const bf16x8*)&Ps[w][l16][quad * 8];
    bf16x8 bp1 = *(const bf16x8*)&Ps[w][l16][32 + quad * 8];

    // O^T += V^T_tile · P ; frag i: d = i*16+quad*4+r, q = l16
#pragma unroll
    for (int i = 0; i < 4; i++) {
      bf16x8 vf0 = *(const bf16x8*)&Vs[i * 16 + l16][quad * 8];
      bf16x8 vf1 = *(const bf16x8*)&Vs[i * 16 + l16][32 + quad * 8];
      o[i] = __builtin_amdgcn_mfma_f32_16x16x32_bf16(vf0, bp0, o[i], 0, 0, 0);
      o[i] = __builtin_amdgcn_mfma_f32_16x16x32_bf16(vf1, bp1, o[i], 0, 0, 0);
    }
  }

  lsum += __shfl_xor(lsum, 16, 64);
  lsum += __shfl_xor(lsum, 32, 64);
  float inv = 1.0f / lsum;

#pragma unroll
  for (int i = 0; i < 4; i++) {
    bf16x4 ov;
#pragma unroll
    for (int r = 0; r < 4; r++) ov[r] = (bf16)(o[i][r] * inv);
    *(bf16x4*)(qb + qrow + i * 16 + quad * 4) = ov;
  }
}

// ---------------------------------------------------------------- launcher
extern "C" void kernel_launch(void* const* d_in, const int* in_sizes, int n_in,
                              void* d_out, int out_size, void* d_ws, size_t ws_size,
                              hipStream_t stream) {
  (void)in_sizes; (void)n_in; (void)out_size; (void)ws_size;
  const float* x     = (const float*)d_in[0];
  const float* w_qkv = (const float*)d_in[1];
  const float* b_qkv = (const float*)d_in[2];
  const float* q_g   = (const float*)d_in[3];
  const float* k_g   = (const float*)d_in[4];
  const float* w_out = (const float*)d_in[5];
  const float* b_out = (const float*)d_in[6];
  float* out = (float*)d_out;

  char* ws = (char*)d_ws;
  bf16* wqkvT = (bf16*)ws; ws += (long)3072 * 1024 * 2;      // 6 MB
  bf16* woT   = (bf16*)ws; ws += (long)1024 * 1024 * 2;      // 2 MB
  bf16* xb    = (bf16*)ws; ws += (long)8192 * 1024 * 2;      // 16 MB
  bf16* qb    = (bf16*)ws; ws += (long)128 * 1024 * 64 * 2;  // 16 MB (q, then attention O)
  bf16* kb    = (bf16*)ws; ws += (long)128 * 1024 * 64 * 2;  // 16 MB
  bf16* vT    = (bf16*)ws; ws += (long)128 * 64 * 1024 * 2;  // 16 MB   (total 72 MB)

  cast_k<<<4096, 256, 0, stream>>>(x, xb);
  transpose_cast_k<<<dim3(3072 / 32, 1024 / 32), 256, 0, stream>>>(w_qkv, wqkvT, 1024, 3072);
  transpose_cast_k<<<dim3(1024 / 32, 1024 / 32), 256, 0, stream>>>(w_out, woT, 1024, 1024);
  gemm_bt<0><<<dim3(3072 / 128, 8192 / 128), 256, 0, stream>>>(xb, wqkvT, b_qkv,
                                                               8192, 3072, 1024,
                                                               (float*)nullptr, qb, kb, vT);
  prep_k<<<dim3(131072 / 4), 256, 0, stream>>>(qb, kb, q_g, k_g);
  attn_k<<<dim3(16, 128), 256, 0, stream>>>(qb, kb, vT);
  gemm_bt<1><<<dim3(1024 / 128, 8192 / 128), 256, 0, stream>>>(qb, woT, b_out,
                                                               8192, 1024, 1024,
                                                               out, (bf16*)nullptr,
                                                               (bf16*)nullptr, (bf16*)nullptr);
}

// Round 5
// 325.538 us; speedup vs baseline: 1.4269x; 1.0701x over previous
//
#include <hip/hip_runtime.h>
#include <hip/hip_bf16.h>
#include <cstdint>

typedef __bf16 bf16;
typedef __bf16 bf16x8 __attribute__((ext_vector_type(8)));
typedef __bf16 bf16x4 __attribute__((ext_vector_type(4)));
typedef float f32x4 __attribute__((ext_vector_type(4)));

__device__ inline bf16x8 cvt8(const float* __restrict__ p) {
  float4 a = *(const float4*)p;
  float4 b = *(const float4*)(p + 4);
  bf16x8 r;
  r[0] = (bf16)a.x; r[1] = (bf16)a.y; r[2] = (bf16)a.z; r[3] = (bf16)a.w;
  r[4] = (bf16)b.x; r[5] = (bf16)b.y; r[6] = (bf16)b.z; r[7] = (bf16)b.w;
  return r;
}

// async global->LDS, 16B per lane; LDS dest = wave-uniform base + lane*16 (m97/m104)
__device__ inline void gl_lds16(const bf16* g, bf16* l) {
  auto gp = reinterpret_cast<const __attribute__((address_space(1))) uint32_t*>(
      reinterpret_cast<uintptr_t>(g));
  auto lp = reinterpret_cast<__attribute__((address_space(3))) uint32_t*>(
      reinterpret_cast<uintptr_t>(l));
  __builtin_amdgcn_global_load_lds(gp, lp, 16, 0, 0);
}

// ---------------------------------------------------------------- fp32 -> bf16 cast
__global__ __launch_bounds__(256) void cast_k(const float* __restrict__ in,
                                              bf16* __restrict__ out) {
  long i = ((long)blockIdx.x * 256 + threadIdx.x) * 8;
  *(bf16x8*)(out + i) = cvt8(in + i);
}

// ---------------------------------------------------------------- transpose + fp32->bf16 cast
__global__ __launch_bounds__(256) void transpose_cast_k(const float* __restrict__ in,
                                                        bf16* __restrict__ out,
                                                        int R, int C) {
  __shared__ bf16 T[32][33];
  int tc = blockIdx.x * 32, tr = blockIdx.y * 32;
  int c = threadIdx.x & 31, r8 = threadIdx.x >> 5;
#pragma unroll
  for (int i = 0; i < 4; i++) {
    int r = r8 + i * 8;
    T[r][c] = (bf16)in[(long)(tr + r) * C + tc + c];
  }
  __syncthreads();
#pragma unroll
  for (int i = 0; i < 4; i++) {
    int r = r8 + i * 8;
    out[(long)(tc + r) * R + tr + c] = T[c][r];
  }
}

// ---------------------------------------------------------------- GEMM (A MxK bf16, Bt NxK bf16)
// BK=64, XOR-swizzled LDS: lane loads global chunk (lane&7)^(lane>>3) so that
// LDS[row][chunk c] = global chunk c^(row&7); fragment reads use chunk (kk*4+quad)^(l16&7)
// -> 2-way bank aliasing only (free, m136). Staged via global_load_lds_dwordx4.
// EPI==0: A = xb; epilogue FUSES QK prep (bias+RMSNorm+RoPE+l2+scale) for q/k regions,
//         scatters v into vT(b,h,d,n).
// EPI==1: A = attention-out in (b,h,tok,d) layout (qb buffer), remapped loads; fp32 C write
template <int EPI>
__global__ __launch_bounds__(256) void gemm_bt(const bf16* __restrict__ A,
                                               const bf16* __restrict__ Bt,
                                               const float* __restrict__ bias,
                                               int M, int N, int K,
                                               float* __restrict__ out,
                                               bf16* __restrict__ qb,
                                               bf16* __restrict__ kb,
                                               bf16* __restrict__ vT,
                                               const float* __restrict__ qg,
                                               const float* __restrict__ kg) {
  __shared__ __align__(16) bf16 As[128][64];  // 128B row stride, swizzled chunks
  __shared__ __align__(16) bf16 Bs[128][64];

  const int tid = threadIdx.x;
  const int lane = tid & 63;
  const int w = tid >> 6;
  const int wm = (w & 1) * 64;
  const int wn = (w >> 1) * 64;
  const int quad = lane >> 4;
  const int l16 = lane & 15;
  const int sw = l16 & 7;

  const int m0 = blockIdx.y * 128;
  const int n0 = blockIdx.x * 128;

  // staging: per DMA call 8 rows x 128B; lane -> row=lane>>3, swizzled chunk
  const int srow = lane >> 3;
  const int gch = (lane & 7) ^ srow;  // global 8-elem chunk this lane fetches

  f32x4 acc[4][4];
#pragma unroll
  for (int i = 0; i < 4; i++)
#pragma unroll
    for (int j = 0; j < 4; j++) acc[i][j] = f32x4{0.f, 0.f, 0.f, 0.f};

  for (int k0 = 0; k0 < K; k0 += 64) {
    __syncthreads();
#pragma unroll
    for (int c = 0; c < 4; c++) {
      int r = w * 32 + c * 8 + srow;
      const bf16* ga;
      if (EPI == 0) {
        ga = A + (long)(m0 + r) * K + k0 + gch * 8;
      } else {
        // A row m, col k -> ((b*16+h)*1024+tok)*64+dc ; h=k0>>6 (uniform), dc=gch*8
        int m1 = m0 + r;
        ga = A + ((long)((m1 >> 10) * 16 + (k0 >> 6)) * 1024 + (m1 & 1023)) * 64 + gch * 8;
      }
      gl_lds16(ga, &As[w * 32 + c * 8][0]);
      gl_lds16(Bt + (long)(n0 + r) * K + k0 + gch * 8, &Bs[w * 32 + c * 8][0]);
    }
    __syncthreads();

#pragma unroll
    for (int kk = 0; kk < 2; kk++) {
      bf16x8 af[4], bfr[4];
#pragma unroll
      for (int i = 0; i < 4; i++) {
        af[i] = *(const bf16x8*)&As[wm + i * 16 + l16][((kk * 4 + quad) ^ sw) * 8];
        bfr[i] = *(const bf16x8*)&Bs[wn + i * 16 + l16][((kk * 4 + quad) ^ sw) * 8];
      }
#pragma unroll
      for (int i = 0; i < 4; i++)
#pragma unroll
        for (int j = 0; j < 4; j++)
          acc[i][j] = __builtin_amdgcn_mfma_f32_16x16x32_bf16(af[i], bfr[j], acc[i][j], 0, 0, 0);
    }
  }

  // ---------------- epilogue: C[row=quad*4+r][col=l16] per frag (m89/m91 layout)
  if (EPI == 1) {
#pragma unroll
    for (int i = 0; i < 4; i++)
#pragma unroll
      for (int j = 0; j < 4; j++)
#pragma unroll
        for (int r = 0; r < 4; r++) {
          int mg = m0 + wm + i * 16 + quad * 4 + r;
          int ng = n0 + wn + j * 16 + l16;
          out[(long)mg * N + ng] = acc[i][j][r] + bias[ng];
        }
    return;
  }

  const int which = n0 >> 10;  // 0=q, 1=k, 2=v (128 | 1024 so block is in one region)
  if (which == 2) {
    // v: scatter into vT(b,h,d,n)
#pragma unroll
    for (int i = 0; i < 4; i++)
#pragma unroll
      for (int j = 0; j < 4; j++)
#pragma unroll
        for (int r = 0; r < 4; r++) {
          int mg = m0 + wm + i * 16 + quad * 4 + r;
          int ng = n0 + wn + j * 16 + l16;
          int rem = ng & 1023, head = rem >> 6, dc = rem & 63;
          int bh = (mg >> 10) * 16 + head;
          vT[((long)bh * 64 + dc) * 1024 + (mg & 1023)] = (bf16)(acc[i][j][r] + bias[ng]);
        }
    return;
  }

  // q/k: fused bias + RMSNorm + 2D RoPE + l2-normalize (+8x fold for q).
  // This wave's 4 j-frags hold channels ch = j*16+l16 of ONE head:
  const float* gg = which ? kg : qg;
  bf16* dst = which ? kb : qb;
  const float fold = which ? 1.0f : 8.0f;
  const int h = ((n0 + wn) & 1023) >> 6;
  const int bh = (m0 >> 10) * 16 + h;
  float bj[4], gain[4];
#pragma unroll
  for (int j = 0; j < 4; j++) {
    bj[j] = bias[n0 + wn + j * 16 + l16];
    gain[j] = gg[j * 16 + l16];
  }
  const float f = exp2f((float)l16 * (-13.287712379549449f / 16.0f));  // 10000^(-l16/16)

#pragma unroll
  for (int i = 0; i < 4; i++) {
#pragma unroll
    for (int r = 0; r < 4; r++) {
      int ntok = (m0 & 1023) + wm + i * 16 + quad * 4 + r;
      float v0 = acc[i][0][r] + bj[0];
      float v1 = acc[i][1][r] + bj[1];
      float v2 = acc[i][2][r] + bj[2];
      float v3 = acc[i][3][r] + bj[3];
      // RMSNorm over d=64 (reduce over the 16 l16 lanes; each holds 4 channels)
      float ss = v0 * v0 + v1 * v1 + v2 * v2 + v3 * v3;
#pragma unroll
      for (int m = 1; m <= 8; m <<= 1) ss += __shfl_xor(ss, m, 64);
      float rms = rsqrtf(ss * (1.0f / 64.0f) + 1e-6f);
      v0 *= rms * gain[0]; v1 *= rms * gain[1]; v2 *= rms * gain[2]; v3 *= rms * gain[3];
      // 2D axial RoPE: ch<32 angle = pos*freq (h for ch<16, w for 16..31); partner ch±32
      float sh, ch_, swv, cw;
      __sincosf((float)(ntok >> 5) * f, &sh, &ch_);
      __sincosf((float)(ntok & 31) * f, &swv, &cw);
      float w0 = v0 * ch_ - v2 * sh;
      float w1 = v1 * cw - v3 * swv;
      float w2 = v2 * ch_ + v0 * sh;
      float w3 = v3 * cw + v1 * swv;
      // l2 normalize (+ cosine-sim scale fold)
      float nn = w0 * w0 + w1 * w1 + w2 * w2 + w3 * w3;
#pragma unroll
      for (int m = 1; m <= 8; m <<= 1) nn += __shfl_xor(nn, m, 64);
      float inv = rsqrtf(nn) * fold;
      long base = ((long)bh * 1024 + ntok) * 64 + l16;
      dst[base] = (bf16)(w0 * inv);
      dst[base + 16] = (bf16)(w1 * inv);
      dst[base + 32] = (bf16)(w2 * inv);
      dst[base + 48] = (bf16)(w3 * inv);
    }
  }
}

// ---------------------------------------------------------------- flash attention (fixed-max softmax)
// s = 8*cos in [-8,8] -> p = exp(s-8); S^T = K·Q^T so lane's C-column is one query.
// block = (bh, 64-query tile); wave = 16 queries; K-tile = 64 keys. O overwrites qb in-place.
__global__ __launch_bounds__(256) void attn_k(bf16* __restrict__ qb,
                                              const bf16* __restrict__ kb,
                                              const bf16* __restrict__ vT) {
  __shared__ __align__(16) bf16 Ks[64][72];     // keys x d
  __shared__ __align__(16) bf16 Vs[64][72];     // d x keys
  __shared__ __align__(16) bf16 Ps[4][16][72];  // per-wave P[q][key]

  const int tid = threadIdx.x;
  const int lane = tid & 63;
  const int w = tid >> 6;
  const int quad = lane >> 4;
  const int l16 = lane & 15;

  const int bh = blockIdx.y;
  const int q0 = blockIdx.x * 64 + w * 16;

  const long qrow = ((long)bh * 1024 + q0 + l16) * 64;
  bf16x8 aq0 = *(const bf16x8*)(qb + qrow + quad * 8);
  bf16x8 aq1 = *(const bf16x8*)(qb + qrow + 32 + quad * 8);

  f32x4 o[4];
#pragma unroll
  for (int i = 0; i < 4; i++) o[i] = f32x4{0.f, 0.f, 0.f, 0.f};
  float lsum = 0.0f;

  const int sr = tid >> 3, sc = (tid & 7) * 8;  // staging: 32 rows x 64 cols per pass
  const bf16* kbase = kb + (long)bh * 65536;
  const bf16* vbase = vT + (long)bh * 65536;

  for (int kt = 0; kt < 1024; kt += 64) {
    __syncthreads();
    *(bf16x8*)&Ks[sr][sc]      = *(const bf16x8*)(kbase + (long)(kt + sr) * 64 + sc);
    *(bf16x8*)&Ks[sr + 32][sc] = *(const bf16x8*)(kbase + (long)(kt + sr + 32) * 64 + sc);
    *(bf16x8*)&Vs[sr][sc]      = *(const bf16x8*)(vbase + (long)sr * 1024 + kt + sc);
    *(bf16x8*)&Vs[sr + 32][sc] = *(const bf16x8*)(vbase + (long)(sr + 32) * 1024 + kt + sc);
    __syncthreads();

    // St = K_tile · Q^T (64 keys x 16 q); frag i: key = i*16+quad*4+r, q = l16
#pragma unroll
    for (int i = 0; i < 4; i++) {
      f32x4 st = f32x4{0.f, 0.f, 0.f, 0.f};
      bf16x8 kf0 = *(const bf16x8*)&Ks[i * 16 + l16][quad * 8];
      bf16x8 kf1 = *(const bf16x8*)&Ks[i * 16 + l16][32 + quad * 8];
      st = __builtin_amdgcn_mfma_f32_16x16x32_bf16(kf0, aq0, st, 0, 0, 0);
      st = __builtin_amdgcn_mfma_f32_16x16x32_bf16(kf1, aq1, st, 0, 0, 0);
      bf16x4 pk;
#pragma unroll
      for (int r = 0; r < 4; r++) {
        float p = __expf(st[r] - 8.0f);
        lsum += p;
        pk[r] = (bf16)p;
      }
      *(bf16x4*)&Ps[w][l16][i * 16 + quad * 4] = pk;
    }
    asm volatile("s_waitcnt lgkmcnt(0)" ::: "memory");

    bf16x8 bp0 = *(const bf16x8*)&Ps[w][l16][quad * 8];
    bf16x8 bp1 = *(const bf16x8*)&Ps[w][l16][32 + quad * 8];

    // O^T += V^T_tile · P ; frag i: d = i*16+quad*4+r, q = l16
#pragma unroll
    for (int i = 0; i < 4; i++) {
      bf16x8 vf0 = *(const bf16x8*)&Vs[i * 16 + l16][quad * 8];
      bf16x8 vf1 = *(const bf16x8*)&Vs[i * 16 + l16][32 + quad * 8];
      o[i] = __builtin_amdgcn_mfma_f32_16x16x32_bf16(vf0, bp0, o[i], 0, 0, 0);
      o[i] = __builtin_amdgcn_mfma_f32_16x16x32_bf16(vf1, bp1, o[i], 0, 0, 0);
    }
  }

  lsum += __shfl_xor(lsum, 16, 64);
  lsum += __shfl_xor(lsum, 32, 64);
  float inv = 1.0f / lsum;

#pragma unroll
  for (int i = 0; i < 4; i++) {
    bf16x4 ov;
#pragma unroll
    for (int r = 0; r < 4; r++) ov[r] = (bf16)(o[i][r] * inv);
    *(bf16x4*)(qb + qrow + i * 16 + quad * 4) = ov;
  }
}

// ---------------------------------------------------------------- launcher
extern "C" void kernel_launch(void* const* d_in, const int* in_sizes, int n_in,
                              void* d_out, int out_size, void* d_ws, size_t ws_size,
                              hipStream_t stream) {
  (void)in_sizes; (void)n_in; (void)out_size; (void)ws_size;
  const float* x     = (const float*)d_in[0];
  const float* w_qkv = (const float*)d_in[1];
  const float* b_qkv = (const float*)d_in[2];
  const float* q_g   = (const float*)d_in[3];
  const float* k_g   = (const float*)d_in[4];
  const float* w_out = (const float*)d_in[5];
  const float* b_out = (const float*)d_in[6];
  float* out = (float*)d_out;

  char* ws = (char*)d_ws;
  bf16* wqkvT = (bf16*)ws; ws += (long)3072 * 1024 * 2;      // 6 MB
  bf16* woT   = (bf16*)ws; ws += (long)1024 * 1024 * 2;      // 2 MB
  bf16* xb    = (bf16*)ws; ws += (long)8192 * 1024 * 2;      // 16 MB
  bf16* qb    = (bf16*)ws; ws += (long)128 * 1024 * 64 * 2;  // 16 MB (q, then attention O)
  bf16* kb    = (bf16*)ws; ws += (long)128 * 1024 * 64 * 2;  // 16 MB
  bf16* vT    = (bf16*)ws; ws += (long)128 * 64 * 1024 * 2;  // 16 MB   (total 72 MB)

  cast_k<<<4096, 256, 0, stream>>>(x, xb);
  transpose_cast_k<<<dim3(3072 / 32, 1024 / 32), 256, 0, stream>>>(w_qkv, wqkvT, 1024, 3072);
  transpose_cast_k<<<dim3(1024 / 32, 1024 / 32), 256, 0, stream>>>(w_out, woT, 1024, 1024);
  gemm_bt<0><<<dim3(3072 / 128, 8192 / 128), 256, 0, stream>>>(xb, wqkvT, b_qkv,
                                                               8192, 3072, 1024,
                                                               (float*)nullptr, qb, kb, vT,
                                                               q_g, k_g);
  attn_k<<<dim3(16, 128), 256, 0, stream>>>(qb, kb, vT);
  gemm_bt<1><<<dim3(1024 / 128, 8192 / 128), 256, 0, stream>>>(qb, woT, b_out,
                                                               8192, 1024, 1024,
                                                               out, (bf16*)nullptr,
                                                               (bf16*)nullptr, (bf16*)nullptr,
                                                               (const float*)nullptr,
                                                               (const float*)nullptr);
}

// Round 6
// 306.380 us; speedup vs baseline: 1.5161x; 1.0625x over previous
//
#include <hip/hip_runtime.h>
#include <hip/hip_bf16.h>
#include <cstdint>

typedef __bf16 bf16;
typedef __bf16 bf16x8 __attribute__((ext_vector_type(8)));
typedef __bf16 bf16x4 __attribute__((ext_vector_type(4)));
typedef float f32x4 __attribute__((ext_vector_type(4)));

__device__ inline bf16x8 cvt8(const float* __restrict__ p) {
  float4 a = *(const float4*)p;
  float4 b = *(const float4*)(p + 4);
  bf16x8 r;
  r[0] = (bf16)a.x; r[1] = (bf16)a.y; r[2] = (bf16)a.z; r[3] = (bf16)a.w;
  r[4] = (bf16)b.x; r[5] = (bf16)b.y; r[6] = (bf16)b.z; r[7] = (bf16)b.w;
  return r;
}

// async global->LDS, 16B per lane; LDS dest = wave-uniform base + lane*16 (m97/m104)
__device__ inline void gl_lds16(const bf16* g, bf16* l) {
  auto gp = reinterpret_cast<const __attribute__((address_space(1))) uint32_t*>(
      reinterpret_cast<uintptr_t>(g));
  auto lp = reinterpret_cast<__attribute__((address_space(3))) uint32_t*>(
      reinterpret_cast<uintptr_t>(l));
  __builtin_amdgcn_global_load_lds(gp, lp, 16, 0, 0);
}

// ---------------------------------------------------------------- fp32 -> bf16 cast
__global__ __launch_bounds__(256) void cast_k(const float* __restrict__ in,
                                              bf16* __restrict__ out) {
  long i = ((long)blockIdx.x * 256 + threadIdx.x) * 8;
  *(bf16x8*)(out + i) = cvt8(in + i);
}

// ---------------------------------------------------------------- transpose + fp32->bf16 cast
__global__ __launch_bounds__(256) void transpose_cast_k(const float* __restrict__ in,
                                                        bf16* __restrict__ out,
                                                        int R, int C) {
  __shared__ bf16 T[32][33];
  int tc = blockIdx.x * 32, tr = blockIdx.y * 32;
  int c = threadIdx.x & 31, r8 = threadIdx.x >> 5;
#pragma unroll
  for (int i = 0; i < 4; i++) {
    int r = r8 + i * 8;
    T[r][c] = (bf16)in[(long)(tr + r) * C + tc + c];
  }
  __syncthreads();
#pragma unroll
  for (int i = 0; i < 4; i++) {
    int r = r8 + i * 8;
    out[(long)(tc + r) * R + tr + c] = T[c][r];
  }
}

// ---------------------------------------------------------------- GEMM (A MxK bf16, Bt NxK bf16)
// m97 structure: BK=32, unpadded 128x32 LDS tiles staged via global_load_lds_dwordx4.
// 16 KB LDS + <=102 VGPR (launch_bounds 5 blocks/CU) — occupancy over conflict-freedom
// (round-5 post-mortem: BK=64 swizzle killed conflicts but cost 2 blocks/CU, net -35%).
// EPI==0: A = xb; epilogue FUSES QK prep (bias+RMSNorm+RoPE+l2+scale) for q/k regions,
//         scatters v into vT(b,h,d,n).
// EPI==1: A = attention-out in (b,h,tok,d) layout (qb buffer), remapped loads; fp32 C write
template <int EPI>
__global__ __launch_bounds__(256, 5) void gemm_bt(const bf16* __restrict__ A,
                                                  const bf16* __restrict__ Bt,
                                                  const float* __restrict__ bias,
                                                  int M, int N, int K,
                                                  float* __restrict__ out,
                                                  bf16* __restrict__ qb,
                                                  bf16* __restrict__ kb,
                                                  bf16* __restrict__ vT,
                                                  const float* __restrict__ qg,
                                                  const float* __restrict__ kg) {
  __shared__ __align__(16) bf16 As[128][32];  // 64B row stride, unpadded (DMA layout)
  __shared__ __align__(16) bf16 Bs[128][32];

  const int tid = threadIdx.x;
  const int lane = tid & 63;
  const int w = tid >> 6;
  const int wm = (w & 1) * 64;
  const int wn = (w >> 1) * 64;
  const int quad = lane >> 4;
  const int l16 = lane & 15;

  const int m0 = blockIdx.y * 128;
  const int n0 = blockIdx.x * 128;

  // staging map: wave w covers rows [w*32, w*32+32) in two 1024B DMA calls;
  // lane -> row = base + (lane>>2), col = (lane&3)*8  => LDS offset = lane*16
  const int sr = w * 32 + (lane >> 2);
  const int sc = (lane & 3) * 8;

  f32x4 acc[4][4];
#pragma unroll
  for (int i = 0; i < 4; i++)
#pragma unroll
    for (int j = 0; j < 4; j++) acc[i][j] = f32x4{0.f, 0.f, 0.f, 0.f};

  for (int k0 = 0; k0 < K; k0 += 32) {
    __syncthreads();
    const bf16 *ga0, *ga1;
    if (EPI == 0) {
      ga0 = A + (long)(m0 + sr) * K + k0 + sc;
      ga1 = ga0 + (long)16 * K;
    } else {
      // A row m, col k -> ((b*16+h)*1024+tok)*64+dc ; h=k0>>6 (uniform over the 32-k tile)
      int hh = k0 >> 6, dc = (k0 & 63) + sc;
      int m1 = m0 + sr, m2 = m1 + 16;
      ga0 = A + ((long)((m1 >> 10) * 16 + hh) * 1024 + (m1 & 1023)) * 64 + dc;
      ga1 = A + ((long)((m2 >> 10) * 16 + hh) * 1024 + (m2 & 1023)) * 64 + dc;
    }
    gl_lds16(ga0, &As[w * 32][0]);
    gl_lds16(ga1, &As[w * 32 + 16][0]);
    gl_lds16(Bt + (long)(n0 + sr) * K + k0 + sc, &Bs[w * 32][0]);
    gl_lds16(Bt + (long)(n0 + sr + 16) * K + k0 + sc, &Bs[w * 32 + 16][0]);
    __syncthreads();  // compiler emits s_waitcnt vmcnt(0) before s_barrier

    bf16x8 af[4], bfr[4];
#pragma unroll
    for (int i = 0; i < 4; i++) {
      af[i] = *(const bf16x8*)&As[wm + i * 16 + l16][quad * 8];
      bfr[i] = *(const bf16x8*)&Bs[wn + i * 16 + l16][quad * 8];
    }
#pragma unroll
    for (int i = 0; i < 4; i++)
#pragma unroll
      for (int j = 0; j < 4; j++)
        acc[i][j] = __builtin_amdgcn_mfma_f32_16x16x32_bf16(af[i], bfr[j], acc[i][j], 0, 0, 0);
  }

  // ---------------- epilogue: C[row=quad*4+r][col=l16] per frag (m89/m91 layout)
  if (EPI == 1) {
#pragma unroll
    for (int i = 0; i < 4; i++)
#pragma unroll
      for (int j = 0; j < 4; j++)
#pragma unroll
        for (int r = 0; r < 4; r++) {
          int mg = m0 + wm + i * 16 + quad * 4 + r;
          int ng = n0 + wn + j * 16 + l16;
          out[(long)mg * N + ng] = acc[i][j][r] + bias[ng];
        }
    return;
  }

  const int which = n0 >> 10;  // 0=q, 1=k, 2=v (128 | 1024 so block is in one region)
  if (which == 2) {
    // v: scatter into vT(b,h,d,n)
#pragma unroll
    for (int i = 0; i < 4; i++)
#pragma unroll
      for (int j = 0; j < 4; j++)
#pragma unroll
        for (int r = 0; r < 4; r++) {
          int mg = m0 + wm + i * 16 + quad * 4 + r;
          int ng = n0 + wn + j * 16 + l16;
          int rem = ng & 1023, head = rem >> 6, dc = rem & 63;
          int bh = (mg >> 10) * 16 + head;
          vT[((long)bh * 64 + dc) * 1024 + (mg & 1023)] = (bf16)(acc[i][j][r] + bias[ng]);
        }
    return;
  }

  // q/k: fused bias + RMSNorm + 2D RoPE + l2-normalize (+8x fold for q).
  // This wave's 4 j-frags hold channels ch = j*16+l16 of ONE head:
  const float* gg = which ? kg : qg;
  bf16* dst = which ? kb : qb;
  const float fold = which ? 1.0f : 8.0f;
  const int h = ((n0 + wn) & 1023) >> 6;
  const int bh = (m0 >> 10) * 16 + h;
  float bj[4], gain[4];
#pragma unroll
  for (int j = 0; j < 4; j++) {
    bj[j] = bias[n0 + wn + j * 16 + l16];
    gain[j] = gg[j * 16 + l16];
  }
  const float f = exp2f((float)l16 * (-13.287712379549449f / 16.0f));  // 10000^(-l16/16)

#pragma unroll
  for (int i = 0; i < 4; i++) {
#pragma unroll
    for (int r = 0; r < 4; r++) {
      int ntok = (m0 & 1023) + wm + i * 16 + quad * 4 + r;
      float v0 = acc[i][0][r] + bj[0];
      float v1 = acc[i][1][r] + bj[1];
      float v2 = acc[i][2][r] + bj[2];
      float v3 = acc[i][3][r] + bj[3];
      // RMSNorm over d=64 (reduce over the 16 l16 lanes; each holds 4 channels)
      float ss = v0 * v0 + v1 * v1 + v2 * v2 + v3 * v3;
#pragma unroll
      for (int m = 1; m <= 8; m <<= 1) ss += __shfl_xor(ss, m, 64);
      float rms = rsqrtf(ss * (1.0f / 64.0f) + 1e-6f);
      v0 *= rms * gain[0]; v1 *= rms * gain[1]; v2 *= rms * gain[2]; v3 *= rms * gain[3];
      // 2D axial RoPE: ch<32 angle = pos*freq (h for ch<16, w for 16..31); partner ch±32
      float sh, ch_, swv, cw;
      __sincosf((float)(ntok >> 5) * f, &sh, &ch_);
      __sincosf((float)(ntok & 31) * f, &swv, &cw);
      float w0 = v0 * ch_ - v2 * sh;
      float w1 = v1 * cw - v3 * swv;
      float w2 = v2 * ch_ + v0 * sh;
      float w3 = v3 * cw + v1 * swv;
      // l2 normalize (+ cosine-sim scale fold)
      float nn = w0 * w0 + w1 * w1 + w2 * w2 + w3 * w3;
#pragma unroll
      for (int m = 1; m <= 8; m <<= 1) nn += __shfl_xor(nn, m, 64);
      float inv = rsqrtf(nn) * fold;
      long base = ((long)bh * 1024 + ntok) * 64 + l16;
      dst[base] = (bf16)(w0 * inv);
      dst[base + 16] = (bf16)(w1 * inv);
      dst[base + 32] = (bf16)(w2 * inv);
      dst[base + 48] = (bf16)(w3 * inv);
    }
  }
}

// ---------------------------------------------------------------- flash attention (fixed-max softmax)
// s = 8*cos in [-8,8] -> p = exp(s-8); S^T = K·Q^T so lane's C-column is one query.
// block = (bh, 64-query tile); wave = 16 queries; K-tile = 64 keys. O overwrites qb in-place.
__global__ __launch_bounds__(256) void attn_k(bf16* __restrict__ qb,
                                              const bf16* __restrict__ kb,
                                              const bf16* __restrict__ vT) {
  __shared__ __align__(16) bf16 Ks[64][72];     // keys x d
  __shared__ __align__(16) bf16 Vs[64][72];     // d x keys
  __shared__ __align__(16) bf16 Ps[4][16][72];  // per-wave P[q][key]

  const int tid = threadIdx.x;
  const int lane = tid & 63;
  const int w = tid >> 6;
  const int quad = lane >> 4;
  const int l16 = lane & 15;

  const int bh = blockIdx.y;
  const int q0 = blockIdx.x * 64 + w * 16;

  const long qrow = ((long)bh * 1024 + q0 + l16) * 64;
  bf16x8 aq0 = *(const bf16x8*)(qb + qrow + quad * 8);
  bf16x8 aq1 = *(const bf16x8*)(qb + qrow + 32 + quad * 8);

  f32x4 o[4];
#pragma unroll
  for (int i = 0; i < 4; i++) o[i] = f32x4{0.f, 0.f, 0.f, 0.f};
  float lsum = 0.0f;

  const int sr = tid >> 3, sc = (tid & 7) * 8;  // staging: 32 rows x 64 cols per pass
  const bf16* kbase = kb + (long)bh * 65536;
  const bf16* vbase = vT + (long)bh * 65536;

  for (int kt = 0; kt < 1024; kt += 64) {
    __syncthreads();
    *(bf16x8*)&Ks[sr][sc]      = *(const bf16x8*)(kbase + (long)(kt + sr) * 64 + sc);
    *(bf16x8*)&Ks[sr + 32][sc] = *(const bf16x8*)(kbase + (long)(kt + sr + 32) * 64 + sc);
    *(bf16x8*)&Vs[sr][sc]      = *(const bf16x8*)(vbase + (long)sr * 1024 + kt + sc);
    *(bf16x8*)&Vs[sr + 32][sc] = *(const bf16x8*)(vbase + (long)(sr + 32) * 1024 + kt + sc);
    __syncthreads();

    // St = K_tile · Q^T (64 keys x 16 q); frag i: key = i*16+quad*4+r, q = l16
#pragma unroll
    for (int i = 0; i < 4; i++) {
      f32x4 st = f32x4{0.f, 0.f, 0.f, 0.f};
      bf16x8 kf0 = *(const bf16x8*)&Ks[i * 16 + l16][quad * 8];
      bf16x8 kf1 = *(const bf16x8*)&Ks[i * 16 + l16][32 + quad * 8];
      st = __builtin_amdgcn_mfma_f32_16x16x32_bf16(kf0, aq0, st, 0, 0, 0);
      st = __builtin_amdgcn_mfma_f32_16x16x32_bf16(kf1, aq1, st, 0, 0, 0);
      bf16x4 pk;
#pragma unroll
      for (int r = 0; r < 4; r++) {
        float p = __expf(st[r] - 8.0f);
        lsum += p;
        pk[r] = (bf16)p;
      }
      *(bf16x4*)&Ps[w][l16][i * 16 + quad * 4] = pk;
    }
    asm volatile("s_waitcnt lgkmcnt(0)" ::: "memory");

    bf16x8 bp0 = *(const bf16x8*)&Ps[w][l16][quad * 8];
    bf16x8 bp1 = *(const bf16x8*)&Ps[w][l16][32 + quad * 8];

    // O^T += V^T_tile · P ; frag i: d = i*16+quad*4+r, q = l16
#pragma unroll
    for (int i = 0; i < 4; i++) {
      bf16x8 vf0 = *(const bf16x8*)&Vs[i * 16 + l16][quad * 8];
      bf16x8 vf1 = *(const bf16x8*)&Vs[i * 16 + l16][32 + quad * 8];
      o[i] = __builtin_amdgcn_mfma_f32_16x16x32_bf16(vf0, bp0, o[i], 0, 0, 0);
      o[i] = __builtin_amdgcn_mfma_f32_16x16x32_bf16(vf1, bp1, o[i], 0, 0, 0);
    }
  }

  lsum += __shfl_xor(lsum, 16, 64);
  lsum += __shfl_xor(lsum, 32, 64);
  float inv = 1.0f / lsum;

#pragma unroll
  for (int i = 0; i < 4; i++) {
    bf16x4 ov;
#pragma unroll
    for (int r = 0; r < 4; r++) ov[r] = (bf16)(o[i][r] * inv);
    *(bf16x4*)(qb + qrow + i * 16 + quad * 4) = ov;
  }
}

// ---------------------------------------------------------------- launcher
extern "C" void kernel_launch(void* const* d_in, const int* in_sizes, int n_in,
                              void* d_out, int out_size, void* d_ws, size_t ws_size,
                              hipStream_t stream) {
  (void)in_sizes; (void)n_in; (void)out_size; (void)ws_size;
  const float* x     = (const float*)d_in[0];
  const float* w_qkv = (const float*)d_in[1];
  const float* b_qkv = (const float*)d_in[2];
  const float* q_g   = (const float*)d_in[3];
  const float* k_g   = (const float*)d_in[4];
  const float* w_out = (const float*)d_in[5];
  const float* b_out = (const float*)d_in[6];
  float* out = (float*)d_out;

  char* ws = (char*)d_ws;
  bf16* wqkvT = (bf16*)ws; ws += (long)3072 * 1024 * 2;      // 6 MB
  bf16* woT   = (bf16*)ws; ws += (long)1024 * 1024 * 2;      // 2 MB
  bf16* xb    = (bf16*)ws; ws += (long)8192 * 1024 * 2;      // 16 MB
  bf16* qb    = (bf16*)ws; ws += (long)128 * 1024 * 64 * 2;  // 16 MB (q, then attention O)
  bf16* kb    = (bf16*)ws; ws += (long)128 * 1024 * 64 * 2;  // 16 MB
  bf16* vT    = (bf16*)ws; ws += (long)128 * 64 * 1024 * 2;  // 16 MB   (total 72 MB)

  cast_k<<<4096, 256, 0, stream>>>(x, xb);
  transpose_cast_k<<<dim3(3072 / 32, 1024 / 32), 256, 0, stream>>>(w_qkv, wqkvT, 1024, 3072);
  transpose_cast_k<<<dim3(1024 / 32, 1024 / 32), 256, 0, stream>>>(w_out, woT, 1024, 1024);
  gemm_bt<0><<<dim3(3072 / 128, 8192 / 128), 256, 0, stream>>>(xb, wqkvT, b_qkv,
                                                               8192, 3072, 1024,
                                                               (float*)nullptr, qb, kb, vT,
                                                               q_g, k_g);
  attn_k<<<dim3(16, 128), 256, 0, stream>>>(qb, kb, vT);
  gemm_bt<1><<<dim3(1024 / 128, 8192 / 128), 256, 0, stream>>>(qb, woT, b_out,
                                                               8192, 1024, 1024,
                                                               out, (bf16*)nullptr,
                                                               (bf16*)nullptr, (bf16*)nullptr,
                                                               (const float*)nullptr,
                                                               (const float*)nullptr);
}